// Round 12
// baseline (403.953 us; speedup 1.0000x reference)
//
#include <hip/hip_runtime.h>
#include <math.h>

#define N_   10000
#define E_   80000
#define O_   10
#define B_   16
#define OUT_ 16
#define NROW_ (N_*O_)    // 100000
#define NITEM_ (E_*O_)   // 800000

typedef __attribute__((ext_vector_type(8))) short bf16x8;
typedef __attribute__((ext_vector_type(4))) short bf16x4;
typedef __attribute__((ext_vector_type(4))) float f32x4;

#define MFMA16(a,b,c) __builtin_amdgcn_mfma_f32_16x16x32_bf16(a,b,c,0,0,0)

__device__ __forceinline__ float gelu_f(float x) {
    float u = fmaf(0.044715f, x * x, 1.0f);
    float e = __builtin_amdgcn_exp2f(2.3022083f * x * u);
    float r = __builtin_amdgcn_rcpf(e + 1.0f);
    return fmaf(-x, r, x);
}

__device__ __forceinline__ unsigned short f2bf(float f) {
    union { float f; unsigned int u; } v; v.f = f;
    unsigned int r = v.u + 0x7FFFu + ((v.u >> 16) & 1u);
    return (unsigned short)(r >> 16);
}
__device__ __forceinline__ float bf2f(unsigned short u) {
    union { unsigned int u; float f; } v; v.u = ((unsigned int)u) << 16;
    return v.f;
}
__device__ __forceinline__ unsigned int cvtpk(float lo, float hi) {
    unsigned int r;
    asm("v_cvt_pk_bf16_f32 %0, %1, %2" : "=v"(r) : "v"(lo), "v"(hi));
    return r;
}
__device__ __forceinline__ bf16x4 pack4(float a, float b, float c, float d) {
    union { unsigned int u[2]; bf16x4 v; } z;
    z.u[0] = cvtpk(a, b);
    z.u[1] = cvtpk(c, d);
    return z.v;
}

__device__ __forceinline__ void fib_vec(int idx, float& vx, float& vy, float& vz) {
    float i = (float)idx + 0.5f;
    float phi = acosf(1.0f - 2.0f * i / (float)O_);
    float theta = 3.14159265358979323846f * (1.0f + 2.2360679774997896964f) * i;
    float sp = sinf(phi);
    vx = cosf(theta) * sp; vy = sinf(theta) * sp; vz = cosf(phi);
}

// ---------------------------------------------------------------------------
// Parallel weight frag-pack (one thread per element) + orientations.
// ---------------------------------------------------------------------------
__global__ __launch_bounds__(256) void k_pack(
    const float* __restrict__ bw1, const float* __restrict__ bw2,
    const float* __restrict__ ckw, const float* __restrict__ l1w,
    const float* __restrict__ l2w, const float* __restrict__ row_w,
    float* __restrict__ orig,
    unsigned short* __restrict__ wW1P, unsigned short* __restrict__ wW2P,
    unsigned short* __restrict__ wCKP, unsigned short* __restrict__ wL1P,
    unsigned short* __restrict__ wL2P, unsigned short* __restrict__ wROP)
{
    const int g = blockIdx.x * 256 + threadIdx.x;
    if (g < 2048) {                                   // W1 (folded): M=64,K=32
        int idx = g;
        int t = idx >> 9, rem = idx & 511;
        int ln = rem >> 3, j = rem & 7;
        int row = t*16 + (ln & 15);
        int k = (ln >> 4)*8 + j;
        float s = 0.0f;
        if (k < 14) {
            const int moff[14] = {0,1,2,3,5,6,7,10,13,14,15,19,25,29};
            const int mcnt[14] = {1,1,1,2,1,1,3,3,1,1,4,6,4,1};
            const int mlist[30] = {0,1,2,3,4,5,6,7,8,10,9,11,12,13,14,
                                   15,16,18,22,17,19,20,23,24,26,21,25,27,28,29};
            for (int q = 0; q < mcnt[k]; ++q) s += bw1[mlist[moff[k]+q]*64 + row];
        }
        wW1P[idx] = f2bf(s);
    } else if (g < 6144) {                            // W2: M=64,K=64
        int idx = g - 2048;
        int t = idx >> 9, rem = idx & 511;
        int mt = t >> 1, ks = t & 1;
        int ln = rem >> 3, j = rem & 7;
        int row = mt*16 + (ln & 15);
        int k = ks*32 + (ln >> 4)*8 + j;
        wW2P[idx] = f2bf(bw2[k*64 + row]);
    } else if (g < 14336) {                           // CK[l]: M=64,K=64
        int idx = g - 6144;
        int l = idx >> 12, r2 = idx & 4095;
        int t = r2 >> 9, rem = r2 & 511;
        int mt = t >> 1, ks = t & 1;
        int ln = rem >> 3, j = rem & 7;
        int row = mt*16 + (ln & 15);
        int k = ks*32 + (ln >> 4)*8 + j;
        wCKP[idx] = f2bf(ckw[l*4096 + k*64 + row]);
    } else if (g < 47104) {                           // L1[l]: M=256,K=64
        int idx = g - 14336;
        int l = idx >> 14, r2 = idx & 16383;
        int t = r2 >> 9, rem = r2 & 511;
        int mt = t >> 1, ks = t & 1;
        int ln = rem >> 3, j = rem & 7;
        int row = mt*16 + (ln & 15);
        int k = ks*32 + (ln >> 4)*8 + j;
        wL1P[idx] = f2bf(l1w[l*16384 + k*256 + row]);
    } else if (g < 79872) {                           // L2[l]: M=64,K=256
        int idx = g - 47104;
        int l = idx >> 14, r2 = idx & 16383;
        int t = r2 >> 9, rem = r2 & 511;
        int mt2 = t >> 3, ksg = t & 7;
        int ln = rem >> 3, j = rem & 7;
        int row = mt2*16 + (ln & 15);
        int k = ksg*32 + (ln >> 4)*8 + j;
        wL2P[idx] = f2bf(l2w[l*16384 + k*64 + row]);
    } else if (g < 81920) {                           // RO[l]: M=16,K=64
        int idx = g - 79872;
        int l = idx >> 10, r2 = idx & 1023;
        int ks = r2 >> 9, rem = r2 & 511;
        int ln = rem >> 3, j = rem & 7;
        int row = ln & 15;
        int k = ks*32 + (ln >> 4)*8 + j;
        wROP[idx] = f2bf(row_w[l*1024 + k*16 + row]);
    } else if (g < 81920 + O_) {                      // orientations
        int o = g - 81920;
        float vx, vy, vz;
        fib_vec(o, vx, vy, vz);
        orig[o*3+0] = vx; orig[o*3+1] = vy; orig[o*3+2] = vz;
    }
}

// ---------------------------------------------------------------------------
// Fiber-basis precompute: one wave per orientation pair.
// ---------------------------------------------------------------------------
__global__ __launch_bounds__(256) void k_fibpre(
    const float* __restrict__ fw1, const float* __restrict__ fb1,
    const float* __restrict__ fw2, const float* __restrict__ fb2,
    const float* __restrict__ cfw, float* __restrict__ fkg)
{
    __shared__ float sRow[4][64];
    const int wv = threadIdx.x >> 6, lane = threadIdx.x & 63;
    const int pr = blockIdx.x * 4 + wv;
    if (pr >= 100) return;
    const int i = pr / O_, j = pr % O_;
    float ix, iy, iz, jx, jy, jz;
    fib_vec(i, ix, iy, iz);
    fib_vec(j, jx, jy, jz);
    float a = ix*jx + iy*jy + iz*jz;
    float a2 = a*a, a3 = a2*a, a4 = a3*a;
    float v = fb1[lane];
    v = fmaf(a,  fw1[0*64+lane], v);
    v = fmaf(a2, fw1[1*64+lane], v);
    v = fmaf(a3, fw1[2*64+lane], v);
    v = fmaf(a4, fw1[3*64+lane], v);
    sRow[wv][lane] = gelu_f(v);
    float acc = fb2[lane];
    for (int b = 0; b < 64; ++b) acc = fmaf(sRow[wv][b], fw2[b*64+lane], acc);
    sRow[wv][lane] = gelu_f(acc);
    for (int l = 0; l < 2; ++l) {
        float s = 0.0f;
        for (int b = 0; b < 64; ++b) s = fmaf(sRow[wv][b], cfw[l*4096 + b*64 + lane], s);
        fkg[l*6400 + pr*64 + lane] = s;
    }
}

// ---------------------------------------------------------------------------
// Embed: compact hg0[n][c] fp32 (initial h is o-uniform) + bf16 table hbf0.
// ---------------------------------------------------------------------------
__global__ __launch_bounds__(256) void k_embed(
    const float* __restrict__ x, const float* __restrict__ ew,
    float* __restrict__ hg0, unsigned short* __restrict__ hbf0)
{
    int t = blockIdx.x * 256 + threadIdx.x;
    if (t >= N_ * 64) return;
    int n = t >> 6, c = t & 63;
    float v = 0.0f;
#pragma unroll
    for (int k = 0; k < 16; ++k) v = fmaf(x[n*16+k], ew[k*64+c], v);
    hg0[t] = v;
    hbf0[t] = f2bf(v);
}

// ---------------------------------------------------------------------------
__global__ __launch_bounds__(256) void k_hist(const int* __restrict__ ei, int* __restrict__ counts)
{
    int e = blockIdx.x * 256 + threadIdx.x;
    if (e < E_) atomicAdd(&counts[ei[E_ + e]], 1);
}

__global__ __launch_bounds__(1024) void k_scan(
    const int* __restrict__ counts, int* __restrict__ offs, int* __restrict__ cursor)
{
    __shared__ int part[1024];
    int t = threadIdx.x;
    const int CH = 10;
    int base_i = t * CH;
    int s = 0;
#pragma unroll
    for (int i = 0; i < CH; ++i) { int idx = base_i + i; if (idx < N_) s += counts[idx]; }
    part[t] = s;
    __syncthreads();
    for (int off = 1; off < 1024; off <<= 1) {
        int v = (t >= off) ? part[t - off] : 0;
        __syncthreads();
        part[t] += v;
        __syncthreads();
    }
    int run = (t > 0) ? part[t - 1] : 0;
#pragma unroll
    for (int i = 0; i < CH; ++i) {
        int idx = base_i + i;
        if (idx < N_) { offs[idx] = run; cursor[idx] = run; run += counts[idx]; }
    }
    if (t == 1023) offs[N_] = run;
}

__global__ __launch_bounds__(256) void k_scatter(
    const int* __restrict__ ei, const float* __restrict__ pos,
    int* __restrict__ cursor, int* __restrict__ csend, int* __restrict__ crecv,
    float* __restrict__ crel)
{
    int e = blockIdx.x * 256 + threadIdx.x;
    if (e >= E_) return;
    int s = ei[e], r = ei[E_ + e];
    int slot = atomicAdd(&cursor[r], 1);
    csend[slot] = s;
    crecv[slot] = r;
    crel[slot*3+0] = pos[s*3+0] - pos[r*3+0];
    crel[slot*3+1] = pos[s*3+1] - pos[r*3+1];
    crel[slot*3+2] = pos[s*3+2] - pos[r*3+2];
}

// ---------------------------------------------------------------------------
// MFMA stage helpers (single-wave block: rows 0..63 of sData).
// ---------------------------------------------------------------------------
template<int KS>
__device__ __forceinline__ void loadB(
    const unsigned short* sData, int lane, bf16x8 Bf[4][KS])
{
    const int lm = lane & 15, lk = lane >> 4;
#pragma unroll
    for (int nt = 0; nt < 4; ++nt)
#pragma unroll
        for (int ks = 0; ks < KS; ++ks) {
            int r = nt*16 + lm;
            int kb = ks*64 + lk*16;
            Bf[nt][ks] = *(const bf16x8*)((const char*)sData + r*128 + (kb ^ ((r&7)<<4)));
        }
}

template<int KS, bool BIAS, bool GELU>
__device__ __forceinline__ void stageC(
    unsigned short* sData, const bf16x8 Bf[4][KS],
    const unsigned short* __restrict__ Wp, const float* __restrict__ bias, int lane)
{
    const int lm = lane & 15, lk = lane >> 4;
    __builtin_amdgcn_s_setprio(1);
#pragma unroll
    for (int mt = 0; mt < 4; ++mt) {
        bf16x8 Af[KS];
#pragma unroll
        for (int ks = 0; ks < KS; ++ks)
            Af[ks] = *(const bf16x8*)(Wp + ((mt*KS + ks)*64 + lane)*8);
        f32x4 b4 = {0,0,0,0};
        if (BIAS) b4 = *(const f32x4*)(bias + mt*16 + (lk<<2));
#pragma unroll
        for (int nt = 0; nt < 4; ++nt) {
            f32x4 acc = b4;
#pragma unroll
            for (int ks = 0; ks < KS; ++ks) acc = MFMA16(Af[ks], Bf[nt][ks], acc);
            float v0 = acc[0], v1 = acc[1], v2 = acc[2], v3 = acc[3];
            if (GELU) { v0 = gelu_f(v0); v1 = gelu_f(v1); v2 = gelu_f(v2); v3 = gelu_f(v3); }
            bf16x4 pk = pack4(v0, v1, v2, v3);
            int rr = nt*16 + lm;
            int cb = mt*32 + (lk<<3);
            *(bf16x4*)((char*)sData + rr*128 + (cb ^ ((rr&7)<<4))) = pk;
        }
    }
    __builtin_amdgcn_s_setprio(0);
}

// phase 0: per-item monomial features -> sData row tid
__device__ __forceinline__ void phase0(
    unsigned short* sData, int slot, int oo, const float* __restrict__ crel,
    const float* __restrict__ ori, int tid)
{
    float r0 = crel[slot*3+0], r1 = crel[slot*3+1], r2 = crel[slot*3+2];
    float o0 = ori[oo*3+0], o1 = ori[oo*3+1], o2 = ori[oo*3+2];
    float a = r0*o0 + r1*o1 + r2*o2;
    float p0 = fmaf(-a, o0, r0), p1 = fmaf(-a, o1, r1), p2 = fmaf(-a, o2, r2);
    float b = sqrtf(p0*p0 + p1*p1 + p2*p2);
    float a2 = a*a, b2 = b*b, ab = a*b;
    float m[14];
    m[0]=a; m[1]=b; m[2]=a2; m[3]=ab; m[4]=b2;
    m[5]=a2*a; m[6]=a2*b; m[7]=a*b2; m[8]=b2*b;
    m[9]=a2*a2; m[10]=a2*ab; m[11]=a2*b2; m[12]=ab*b2; m[13]=b2*b2;
    unsigned int pk[16];
#pragma unroll
    for (int j = 0; j < 7; ++j) pk[j] = cvtpk(m[2*j], m[2*j+1]);
#pragma unroll
    for (int j = 7; j < 16; ++j) pk[j] = 0;
#pragma unroll
    for (int q = 0; q < 4; ++q) {
        int cb = q*16;
        *(f32x4*)((char*)sData + tid*128 + (cb ^ ((tid&7)<<4))) = ((const f32x4*)pk)[q];
    }
}

// scatter tail: lane=channel.
#define SCATTER_BODY(KC_EXPR)                                                        \
    int prevr = __shfl_up(rcv, 1);                                                   \
    unsigned long long bmask = __ballot(lane > 0 && rcv != prevr);                   \
    float a0=0,a1c=0,a2c=0,a3c=0,a4c=0,a5c=0,a6c=0,a7c=0,a8c=0,a9c=0;                \
    int cur = __builtin_amdgcn_readfirstlane(rcv);                                   \
    int soi = item0 % 10;                                                            \
    _Pragma("unroll")                                                                \
    for (int ch = 0; ch < 4; ++ch) {                                                 \
        unsigned short hvu[16]; float kcv[16];                                       \
        _Pragma("unroll")                                                            \
        for (int j = 0; j < 16; ++j) {                                               \
            const int i = ch*16 + j;                                                 \
            hvu[j] = hb[__builtin_amdgcn_readlane(myaddr, i)];                       \
            kcv[j] = (KC_EXPR);                                                      \
        }                                                                            \
        _Pragma("unroll")                                                            \
        for (int j = 0; j < 16; ++j) {                                               \
            const int i = ch*16 + j;                                                 \
            if (bmask & (1ull << i)) { FLUSH_RUN(cur); cur = __builtin_amdgcn_readlane(rcv, i); } \
            float mv = kcv[j] * bf2f(hvu[j]);                                        \
            if      (soi == 0) a0  += mv;                                            \
            else if (soi == 1) a1c += mv;                                            \
            else if (soi == 2) a2c += mv;                                            \
            else if (soi == 3) a3c += mv;                                            \
            else if (soi == 4) a4c += mv;                                            \
            else if (soi == 5) a5c += mv;                                            \
            else if (soi == 6) a6c += mv;                                            \
            else if (soi == 7) a7c += mv;                                            \
            else if (soi == 8) a8c += mv;                                            \
            else               a9c += mv;                                            \
            soi = (soi == 9) ? 0 : soi + 1;                                          \
        }                                                                            \
    }                                                                                \
    FLUSH_RUN(cur);

#define FLUSH_RUN(R) { float* bp = h1g + (R)*640 + lane; \
    atomicAdd(bp+0,a0); atomicAdd(bp+64,a1c); atomicAdd(bp+128,a2c); atomicAdd(bp+192,a3c); \
    atomicAdd(bp+256,a4c); atomicAdd(bp+320,a5c); atomicAdd(bp+384,a6c); atomicAdd(bp+448,a7c); \
    atomicAdd(bp+512,a8c); atomicAdd(bp+576,a9c); \
    a0=a1c=a2c=a3c=a4c=a5c=a6c=a7c=a8c=a9c=0.0f; }

// ---------------------------------------------------------------------------
// Fallback full k_msg (1 wave/block, 8 KB LDS).  L0: gather hbf0[n][c].
// ---------------------------------------------------------------------------
template<bool L0>
__global__ __launch_bounds__(64) void k_msg(
    const unsigned short* __restrict__ hbf, float* __restrict__ h1g,
    const int* __restrict__ csend, const int* __restrict__ crecv,
    const float* __restrict__ crel, const float* __restrict__ ori,
    const unsigned short* __restrict__ wW1P, const unsigned short* __restrict__ wW2P,
    const unsigned short* __restrict__ wCKP_l,
    const float* __restrict__ bb1, const float* __restrict__ bb2)
{
    __shared__ unsigned short sData[64*64];
    const int lane = threadIdx.x;
    const int item0 = blockIdx.x * 64;
    const int item = item0 + lane;
    const int slot = item / 10;
    const int oo = item - slot * 10;
    const int snd = csend[slot];
    const int rcv = crecv[slot];
    phase0(sData, slot, oo, crel, ori, lane);
    {
        bf16x8 Bf1[4][1]; loadB<1>(sData, lane, Bf1);
        stageC<1, true, true>(sData, Bf1, wW1P, bb1, lane);
    }
    {
        bf16x8 Bf2[4][2]; loadB<2>(sData, lane, Bf2);
        stageC<2, true, true>(sData, Bf2, wW2P, bb2, lane);
    }
    {
        bf16x8 Bf3[4][2]; loadB<2>(sData, lane, Bf3);
        stageC<2, false, false>(sData, Bf3, wCKP_l, (const float*)0, lane);
    }
    const int myaddr = L0 ? (snd * 64) : ((snd * 10 + oo) * 64);
    const unsigned short* hb = hbf + lane;
    const char* vb[8];
#pragma unroll
    for (int k = 0; k < 8; ++k) vb[k] = (const char*)sData + ((lane*2) ^ (k<<4));
    SCATTER_BODY(bf2f(*(const unsigned short*)(vb[j&7] + i*128)))
}

// ---------------------------------------------------------------------------
// Layer-0 dual k_msg: shared stages 1-2, stage3 for BOTH layers; kc1 -> global
// (de-swizzled, coalesced 1KB stores), kc0 -> scatter with hbf0.
// ---------------------------------------------------------------------------
__global__ __launch_bounds__(64) void k_msg0dual(
    const unsigned short* __restrict__ hbf, float* __restrict__ h1g,
    unsigned short* __restrict__ kc1g,
    const int* __restrict__ csend, const int* __restrict__ crecv,
    const float* __restrict__ crel, const float* __restrict__ ori,
    const unsigned short* __restrict__ wW1P, const unsigned short* __restrict__ wW2P,
    const unsigned short* __restrict__ wCK0, const unsigned short* __restrict__ wCK1,
    const float* __restrict__ bb1, const float* __restrict__ bb2)
{
    __shared__ unsigned short sData[64*64];
    const int lane = threadIdx.x;
    const int item0 = blockIdx.x * 64;
    const int item = item0 + lane;
    const int slot = item / 10;
    const int oo = item - slot * 10;
    const int snd = csend[slot];
    const int rcv = crecv[slot];
    phase0(sData, slot, oo, crel, ori, lane);
    {
        bf16x8 Bf1[4][1]; loadB<1>(sData, lane, Bf1);
        stageC<1, true, true>(sData, Bf1, wW1P, bb1, lane);
    }
    {
        bf16x8 Bf2[4][2]; loadB<2>(sData, lane, Bf2);
        stageC<2, true, true>(sData, Bf2, wW2P, bb2, lane);
    }
    bf16x8 Bf3[4][2]; loadB<2>(sData, lane, Bf3);
    // stage3 layer 1 -> kc1g: de-swizzling copy, 1KB contiguous stores.
    stageC<2, false, false>(sData, Bf3, wCK1, (const float*)0, lane);
    {
        char* dst = (char*)kc1g + (size_t)item0 * 128;
#pragma unroll
        for (int q = 0; q < 8; ++q) {
            int g = q*1024 + lane*16;
            int row = g >> 7;
            int off = g & 127;
            f32x4 v = *(const f32x4*)((const char*)sData + row*128 + (off ^ ((row&7)<<4)));
            *(f32x4*)(dst + g) = v;
        }
    }
    // stage3 layer 0 -> scatter
    stageC<2, false, false>(sData, Bf3, wCK0, (const float*)0, lane);
    const int myaddr = snd * 64;
    const unsigned short* hb = hbf + lane;
    const char* vb[8];
#pragma unroll
    for (int k = 0; k < 8; ++k) vb[k] = (const char*)sData + ((lane*2) ^ (k<<4));
    SCATTER_BODY(bf2f(*(const unsigned short*)(vb[j&7] + i*128)))
}

// ---------------------------------------------------------------------------
// Layer-1 lite k_msg: precomputed kc1 (plain row-major) + gather + scatter.
// ---------------------------------------------------------------------------
__global__ __launch_bounds__(64) void k_msg1lite(
    const unsigned short* __restrict__ kc1g, const unsigned short* __restrict__ hbf,
    float* __restrict__ h1g,
    const int* __restrict__ csend, const int* __restrict__ crecv)
{
    const int lane = threadIdx.x;
    const int item0 = blockIdx.x * 64;
    const int item = item0 + lane;
    const int slot = item / 10;
    const int oo = item - slot * 10;
    const int snd = csend[slot];
    const int rcv = crecv[slot];
    const int myaddr = (snd * 10 + oo) * 64;
    const unsigned short* hb = hbf + lane;
    const char* kb = (const char*)kc1g + (size_t)item0 * 128 + lane*2;
    SCATTER_BODY(bf2f(*(const unsigned short*)(kb + (size_t)i*128)))
}
#undef FLUSH_RUN
#undef SCATTER_BODY

// ---------------------------------------------------------------------------
// Fused fiber conv + LayerNorm -> y bf16; optionally zero h1 after read.
// ---------------------------------------------------------------------------
__global__ __launch_bounds__(256) void k_fln(
    float* __restrict__ h1, const float* __restrict__ fkg,
    const float* __restrict__ cb, const float* __restrict__ ns,
    const float* __restrict__ nb, unsigned short* __restrict__ y, int zero_h1)
{
    __shared__ float sFK[6400];
    const int tid = threadIdx.x;
    for (int i = tid; i < 6400; i += 256) sFK[i] = fkg[i];
    __syncthreads();
    const int lane = tid & 63, wv = tid >> 6;
    float cbv = cb[lane], nsv = ns[lane], nbv = nb[lane];
    const int n = blockIdx.x * 4 + wv;
    float hr[10];
#pragma unroll
    for (int o = 0; o < O_; ++o) hr[o] = h1[n*640 + o*64 + lane];
    if (zero_h1) {
#pragma unroll
        for (int o = 0; o < O_; ++o) h1[n*640 + o*64 + lane] = 0.0f;
    }
#pragma unroll
    for (int p = 0; p < O_; ++p) {
        float v = 0.0f;
#pragma unroll
        for (int o = 0; o < O_; ++o) v = fmaf(hr[o], sFK[(p*O_+o)*64 + lane], v);
        v = v * 0.1f + cbv;
        float s = v, q = v*v;
#pragma unroll
        for (int d = 1; d < 64; d <<= 1) { s += __shfl_xor(s, d); q += __shfl_xor(q, d); }
        float mu = s * (1.0f/64.0f);
        float var = q * (1.0f/64.0f) - mu*mu;
        float rs = rsqrtf(var + 1e-6f);
        float yv = (v - mu) * rs * nsv + nbv;
        y[(n*O_ + p)*64 + lane] = f2bf(yv);
    }
}

// ---------------------------------------------------------------------------
// MLP: 128 rows/block (nt=2), frag-packed weights, readout stored.
// LAST=0: residual from compact hg0[n] (o-uniform initial h), write hn to hg
// (fp32) and ybuf (bf16, next layer's gather).  LAST=1: residual from hg,
// no write-back.
// ---------------------------------------------------------------------------
template<int LAST>
__global__ __launch_bounds__(256, 4) void k_mlp(
    unsigned short* ybuf, const float* __restrict__ hread, float* __restrict__ hg,
    float* __restrict__ rout,
    const unsigned short* __restrict__ wL1P_l, const float* __restrict__ l1b_l,
    const unsigned short* __restrict__ wL2P_l, const float* __restrict__ l2b_l,
    const unsigned short* __restrict__ wROP_l, const float* __restrict__ rob_l)
{
    __shared__ unsigned short sA[128*64];
    const int tid = threadIdx.x;
    const int lane = tid & 63, wv = tid >> 6;
    const int rb = blockIdx.x * 128;
#pragma unroll
    for (int i = tid*16; i < 128*128; i += 256*16) {
        int r = i >> 7, off = i & 127;
        int grow = rb + r; if (grow >= NROW_) grow = NROW_ - 1;
        *(f32x4*)((char*)sA + r*128 + (off ^ ((r&7)<<4))) =
            *(const f32x4*)((const char*)ybuf + (size_t)grow*128 + off);
    }
    __syncthreads();
    const int lm = lane & 15, lk = lane >> 4;
    bf16x8 Yf[2][2];
#pragma unroll
    for (int nt = 0; nt < 2; ++nt)
#pragma unroll
        for (int ks = 0; ks < 2; ++ks) {
            int r = wv*32 + nt*16 + lm;
            int kb = ks*64 + lk*16;
            Yf[nt][ks] = *(const bf16x8*)((const char*)sA + r*128 + (kb ^ ((r&7)<<4)));
        }
    f32x4 acc2[4][2];
#pragma unroll
    for (int m = 0; m < 4; ++m) {
        f32x4 b2 = *(const f32x4*)(l2b_l + m*16 + (lk<<2));
#pragma unroll
        for (int nt = 0; nt < 2; ++nt) acc2[m][nt] = b2;
    }
    __builtin_amdgcn_s_setprio(1);
#pragma unroll
    for (int jb = 0; jb < 4; ++jb) {
#pragma unroll
        for (int mt = 0; mt < 4; ++mt) {
            bf16x8 A1[2];
#pragma unroll
            for (int ks = 0; ks < 2; ++ks)
                A1[ks] = *(const bf16x8*)(wL1P_l + (((jb*4 + mt)*2 + ks)*64 + lane)*8);
            f32x4 b4 = *(const f32x4*)(l1b_l + jb*64 + mt*16 + (lk<<2));
#pragma unroll
            for (int nt = 0; nt < 2; ++nt) {
                f32x4 acc = b4;
                acc = MFMA16(A1[0], Yf[nt][0], acc);
                acc = MFMA16(A1[1], Yf[nt][1], acc);
                bf16x4 pk = pack4(gelu_f(acc[0]), gelu_f(acc[1]), gelu_f(acc[2]), gelu_f(acc[3]));
                int rr = wv*32 + nt*16 + lm;
                int cb = mt*32 + (lk<<3);
                *(bf16x4*)((char*)sA + rr*128 + (cb ^ ((rr&7)<<4))) = pk;
            }
        }
        bf16x8 Mf[2][2];
#pragma unroll
        for (int nt = 0; nt < 2; ++nt)
#pragma unroll
            for (int ks = 0; ks < 2; ++ks) {
                int r = wv*32 + nt*16 + lm;
                int kb = ks*64 + lk*16;
                Mf[nt][ks] = *(const bf16x8*)((const char*)sA + r*128 + (kb ^ ((r&7)<<4)));
            }
#pragma unroll
        for (int mt2 = 0; mt2 < 4; ++mt2) {
            bf16x8 A2[2];
#pragma unroll
            for (int ks = 0; ks < 2; ++ks)
                A2[ks] = *(const bf16x8*)(wL2P_l + ((mt2*8 + jb*2 + ks)*64 + lane)*8);
#pragma unroll
            for (int nt = 0; nt < 2; ++nt) {
                acc2[mt2][nt] = MFMA16(A2[0], Mf[nt][0], acc2[mt2][nt]);
                acc2[mt2][nt] = MFMA16(A2[1], Mf[nt][1], acc2[mt2][nt]);
            }
        }
    }
    __builtin_amdgcn_s_setprio(0);
    // epilogue: residual + hn stash
#pragma unroll
    for (int nt = 0; nt < 2; ++nt) {
        const int rloc = wv*32 + nt*16 + lm;
        const int grow = rb + rloc;
        const bool valid = grow < NROW_;
        const int growc = valid ? grow : (NROW_ - 1);
        const size_t hoff = LAST ? ((size_t)growc*64) : ((size_t)(growc/10)*64);
#pragma unroll
        for (int mt2 = 0; mt2 < 4; ++mt2) {
            f32x4 hv = *(const f32x4*)(hread + hoff + mt2*16 + (lk<<2));
            f32x4 hn;
#pragma unroll
            for (int r = 0; r < 4; ++r) hn[r] = hv[r] + acc2[mt2][nt][r];
            bf16x4 pk = pack4(hn[0], hn[1], hn[2], hn[3]);
            if (!LAST && valid) {
                *(f32x4*)(hg + (size_t)grow*64 + mt2*16 + (lk<<2)) = hn;
                *(bf16x4*)((char*)ybuf + (size_t)grow*128 + (mt2*16 + (lk<<2))*2) = pk;
            }
            int cb = mt2*32 + (lk<<3);
            *(bf16x4*)((char*)sA + rloc*128 + (cb ^ ((rloc&7)<<4))) = pk;
        }
    }
    // readout: ro^T hn -> store
    bf16x8 Ro[2];
#pragma unroll
    for (int ks = 0; ks < 2; ++ks)
        Ro[ks] = *(const bf16x8*)(wROP_l + (ks*64 + lane)*8);
    f32x4 rb4 = *(const f32x4*)(rob_l + (lk<<2));
#pragma unroll
    for (int nt = 0; nt < 2; ++nt) {
        const int rloc = wv*32 + nt*16 + lm;
        const int grow = rb + rloc;
        bf16x8 Hf[2];
#pragma unroll
        for (int ks = 0; ks < 2; ++ks) {
            int kb = ks*64 + lk*16;
            Hf[ks] = *(const bf16x8*)((const char*)sA + rloc*128 + (kb ^ ((rloc&7)<<4)));
        }
        f32x4 r4 = rb4;
        r4 = MFMA16(Ro[0], Hf[0], r4);
        r4 = MFMA16(Ro[1], Hf[1], r4);
        if (grow < NROW_) *(f32x4*)(rout + (size_t)grow*16 + (lk<<2)) = r4;
    }
}

// ---------------------------------------------------------------------------
__global__ __launch_bounds__(256) void k_pool(
    const float* __restrict__ r0, const float* __restrict__ r1,
    const int* __restrict__ batch, float* __restrict__ out)
{
    int t = blockIdx.x * 256 + threadIdx.x;
    if (t >= N_ * 16) return;
    int n = t >> 4, j = t & 15;
    float s = 0.0f;
#pragma unroll
    for (int p = 0; p < O_; ++p)
        s += r0[(n*O_ + p)*16 + j] + r1[(n*O_ + p)*16 + j];
    atomicAdd(&out[batch[n]*16 + j], s * (1.0f/20.0f));
}

// ---------------------------------------------------------------------------
extern "C" void kernel_launch(void* const* d_in, const int* in_sizes, int n_in,
                              void* d_out, int out_size, void* d_ws, size_t ws_size,
                              hipStream_t stream)
{
    const float* x    = (const float*)d_in[0];
    const float* pos  = (const float*)d_in[1];
    const float* bw1  = (const float*)d_in[2];
    const float* bb1  = (const float*)d_in[3];
    const float* bw2  = (const float*)d_in[4];
    const float* bb2  = (const float*)d_in[5];
    const float* fw1  = (const float*)d_in[6];
    const float* fb1  = (const float*)d_in[7];
    const float* fw2  = (const float*)d_in[8];
    const float* fb2  = (const float*)d_in[9];
    const float* embw = (const float*)d_in[10];
    const float* ckw  = (const float*)d_in[11];
    const float* cfw  = (const float*)d_in[12];
    const float* cb   = (const float*)d_in[13];
    const float* ns   = (const float*)d_in[14];
    const float* nbp  = (const float*)d_in[15];
    const float* l1w  = (const float*)d_in[16];
    const float* l1b  = (const float*)d_in[17];
    const float* l2w  = (const float*)d_in[18];
    const float* l2b  = (const float*)d_in[19];
    const float* row  = (const float*)d_in[20];
    const float* rob  = (const float*)d_in[21];
    const int*   ei   = (const int*)d_in[22];
    const int*   batch= (const int*)d_in[23];
    float* out = (float*)d_out;

    char* w = (char*)d_ws;
    size_t off = 0;
    auto alloc = [&](size_t bytes) -> char* {
        char* p = w + off; off += (bytes + 255) / 256 * 256; return p;
    };
    float* ori    = (float*)alloc(32 * 4);
    float* fkg    = (float*)alloc(2 * 6400 * 4);
    unsigned short* wW1P = (unsigned short*)alloc(4*512*2);
    unsigned short* wW2P = (unsigned short*)alloc(8*512*2);
    unsigned short* wCKP = (unsigned short*)alloc(2*8*512*2);
    unsigned short* wL1P = (unsigned short*)alloc(2*32*512*2);
    unsigned short* wL2P = (unsigned short*)alloc(2*32*512*2);
    unsigned short* wROP = (unsigned short*)alloc(2*2*512*2);
    float* hg0    = (float*)alloc((size_t)N_ * 64 * 4);
    float* h      = (float*)alloc((size_t)NROW_ * 64 * 4);
    float* h1     = (float*)alloc((size_t)N_ * 640 * 4);
    unsigned short* y = (unsigned short*)alloc((size_t)NROW_ * 64 * 2);
    unsigned short* hbf0 = (unsigned short*)alloc((size_t)N_ * 64 * 2);
    float* rout0  = (float*)alloc((size_t)NROW_ * 16 * 4);
    float* rout1  = (float*)alloc((size_t)NROW_ * 16 * 4);
    float* crel   = (float*)alloc((size_t)E_ * 3 * 4);
    int*   counts = (int*)alloc((N_ + 1) * 4);
    int*   offs   = (int*)alloc((N_ + 1) * 4);
    int*   cursor = (int*)alloc((N_ + 1) * 4);
    int*   csend  = (int*)alloc((size_t)E_ * 4);
    int*   crecv  = (int*)alloc((size_t)E_ * 4);
    // optional kc1 buffer (102.4 MB) -- split path only if workspace allows
    unsigned short* kc1g = nullptr;
    if (ws_size >= off + (size_t)NITEM_ * 64 * 2 + 256)
        kc1g = (unsigned short*)alloc((size_t)NITEM_ * 64 * 2);

    hipMemsetAsync(h1, 0, (size_t)N_ * 640 * 4, stream);
    hipMemsetAsync(out, 0, (size_t)out_size * 4, stream);
    hipMemsetAsync(counts, 0, (N_ + 1) * 4, stream);

    k_pack<<<321, 256, 0, stream>>>(bw1, bw2, ckw, l1w, l2w, row, ori,
                                    wW1P, wW2P, wCKP, wL1P, wL2P, wROP);
    k_fibpre<<<25, 256, 0, stream>>>(fw1, fb1, fw2, fb2, cfw, fkg);
    k_embed<<<(N_ * 64 + 255) / 256, 256, 0, stream>>>(x, embw, hg0, hbf0);
    k_hist<<<(E_ + 255) / 256, 256, 0, stream>>>(ei, counts);
    k_scan<<<1, 1024, 0, stream>>>(counts, offs, cursor);
    k_scatter<<<(E_ + 255) / 256, 256, 0, stream>>>(ei, pos, cursor, csend, crecv, crel);

    for (int l = 0; l < 2; ++l) {
        if (l == 0) {
            if (kc1g)
                k_msg0dual<<<NITEM_ / 64, 64, 0, stream>>>(hbf0, h1, kc1g, csend, crecv,
                                                           crel, ori, wW1P, wW2P,
                                                           wCKP, wCKP + 4096, bb1, bb2);
            else
                k_msg<true><<<NITEM_ / 64, 64, 0, stream>>>(hbf0, h1, csend, crecv, crel, ori,
                                                            wW1P, wW2P, wCKP, bb1, bb2);
        } else {
            if (kc1g)
                k_msg1lite<<<NITEM_ / 64, 64, 0, stream>>>(kc1g, y, h1, csend, crecv);
            else
                k_msg<false><<<NITEM_ / 64, 64, 0, stream>>>(y, h1, csend, crecv, crel, ori,
                                                             wW1P, wW2P, wCKP + 4096, bb1, bb2);
        }
        k_fln<<<N_ / 4, 256, 0, stream>>>(h1, fkg + l*6400, cb + l*64, ns + l*64, nbp + l*64, y,
                                          (l == 0) ? 1 : 0);
        if (l == 0)
            k_mlp<0><<<(NROW_ + 127) / 128, 256, 0, stream>>>(y, hg0, h, rout0,
                                                              wL1P, l1b, wL2P, l2b,
                                                              wROP, rob);
        else
            k_mlp<1><<<(NROW_ + 127) / 128, 256, 0, stream>>>(y, h, h, rout1,
                                                              wL1P + 16384, l1b + 256,
                                                              wL2P + 16384, l2b + 64,
                                                              wROP + 1024, rob + 16);
    }
    k_pool<<<(N_ * 16 + 255) / 256, 256, 0, stream>>>(rout0, rout1, batch, out);
}

// Round 13
// 390.858 us; speedup vs baseline: 1.0335x; 1.0335x over previous
//
#include <hip/hip_runtime.h>
#include <math.h>

#define N_   10000
#define E_   80000
#define O_   10
#define B_   16
#define OUT_ 16
#define NROW_ (N_*O_)    // 100000
#define NITEM_ (E_*O_)   // 800000

typedef __attribute__((ext_vector_type(8))) short bf16x8;
typedef __attribute__((ext_vector_type(4))) short bf16x4;
typedef __attribute__((ext_vector_type(4))) float f32x4;

#define MFMA16(a,b,c) __builtin_amdgcn_mfma_f32_16x16x32_bf16(a,b,c,0,0,0)

__device__ __forceinline__ float gelu_f(float x) {
    float u = fmaf(0.044715f, x * x, 1.0f);
    float e = __builtin_amdgcn_exp2f(2.3022083f * x * u);
    float r = __builtin_amdgcn_rcpf(e + 1.0f);
    return fmaf(-x, r, x);
}

__device__ __forceinline__ unsigned short f2bf(float f) {
    union { float f; unsigned int u; } v; v.f = f;
    unsigned int r = v.u + 0x7FFFu + ((v.u >> 16) & 1u);
    return (unsigned short)(r >> 16);
}
__device__ __forceinline__ float bf2f(unsigned short u) {
    union { unsigned int u; float f; } v; v.u = ((unsigned int)u) << 16;
    return v.f;
}
__device__ __forceinline__ unsigned int cvtpk(float lo, float hi) {
    unsigned int r;
    asm("v_cvt_pk_bf16_f32 %0, %1, %2" : "=v"(r) : "v"(lo), "v"(hi));
    return r;
}
__device__ __forceinline__ bf16x4 pack4(float a, float b, float c, float d) {
    union { unsigned int u[2]; bf16x4 v; } z;
    z.u[0] = cvtpk(a, b);
    z.u[1] = cvtpk(c, d);
    return z.v;
}

__device__ __forceinline__ void fib_vec(int idx, float& vx, float& vy, float& vz) {
    float i = (float)idx + 0.5f;
    float phi = acosf(1.0f - 2.0f * i / (float)O_);
    float theta = 3.14159265358979323846f * (1.0f + 2.2360679774997896964f) * i;
    float sp = sinf(phi);
    vx = cosf(theta) * sp; vy = sinf(theta) * sp; vz = cosf(phi);
}

// ---------------------------------------------------------------------------
// Parallel weight frag-pack (one thread per element) + orientations.
// ---------------------------------------------------------------------------
__global__ __launch_bounds__(256) void k_pack(
    const float* __restrict__ bw1, const float* __restrict__ bw2,
    const float* __restrict__ ckw, const float* __restrict__ l1w,
    const float* __restrict__ l2w, const float* __restrict__ row_w,
    float* __restrict__ orig,
    unsigned short* __restrict__ wW1P, unsigned short* __restrict__ wW2P,
    unsigned short* __restrict__ wCKP, unsigned short* __restrict__ wL1P,
    unsigned short* __restrict__ wL2P, unsigned short* __restrict__ wROP)
{
    const int g = blockIdx.x * 256 + threadIdx.x;
    if (g < 2048) {                                   // W1 (folded): M=64,K=32
        int idx = g;
        int t = idx >> 9, rem = idx & 511;
        int ln = rem >> 3, j = rem & 7;
        int row = t*16 + (ln & 15);
        int k = (ln >> 4)*8 + j;
        float s = 0.0f;
        if (k < 14) {
            const int moff[14] = {0,1,2,3,5,6,7,10,13,14,15,19,25,29};
            const int mcnt[14] = {1,1,1,2,1,1,3,3,1,1,4,6,4,1};
            const int mlist[30] = {0,1,2,3,4,5,6,7,8,10,9,11,12,13,14,
                                   15,16,18,22,17,19,20,23,24,26,21,25,27,28,29};
            for (int q = 0; q < mcnt[k]; ++q) s += bw1[mlist[moff[k]+q]*64 + row];
        }
        wW1P[idx] = f2bf(s);
    } else if (g < 6144) {                            // W2: M=64,K=64
        int idx = g - 2048;
        int t = idx >> 9, rem = idx & 511;
        int mt = t >> 1, ks = t & 1;
        int ln = rem >> 3, j = rem & 7;
        int row = mt*16 + (ln & 15);
        int k = ks*32 + (ln >> 4)*8 + j;
        wW2P[idx] = f2bf(bw2[k*64 + row]);
    } else if (g < 14336) {                           // CK[l]: M=64,K=64
        int idx = g - 6144;
        int l = idx >> 12, r2 = idx & 4095;
        int t = r2 >> 9, rem = r2 & 511;
        int mt = t >> 1, ks = t & 1;
        int ln = rem >> 3, j = rem & 7;
        int row = mt*16 + (ln & 15);
        int k = ks*32 + (ln >> 4)*8 + j;
        wCKP[idx] = f2bf(ckw[l*4096 + k*64 + row]);
    } else if (g < 47104) {                           // L1[l]: M=256,K=64
        int idx = g - 14336;
        int l = idx >> 14, r2 = idx & 16383;
        int t = r2 >> 9, rem = r2 & 511;
        int mt = t >> 1, ks = t & 1;
        int ln = rem >> 3, j = rem & 7;
        int row = mt*16 + (ln & 15);
        int k = ks*32 + (ln >> 4)*8 + j;
        wL1P[idx] = f2bf(l1w[l*16384 + k*256 + row]);
    } else if (g < 79872) {                           // L2[l]: M=64,K=256
        int idx = g - 47104;
        int l = idx >> 14, r2 = idx & 16383;
        int t = r2 >> 9, rem = r2 & 511;
        int mt2 = t >> 3, ksg = t & 7;
        int ln = rem >> 3, j = rem & 7;
        int row = mt2*16 + (ln & 15);
        int k = ksg*32 + (ln >> 4)*8 + j;
        wL2P[idx] = f2bf(l2w[l*16384 + k*64 + row]);
    } else if (g < 81920) {                           // RO[l]: M=16,K=64
        int idx = g - 79872;
        int l = idx >> 10, r2 = idx & 1023;
        int ks = r2 >> 9, rem = r2 & 511;
        int ln = rem >> 3, j = rem & 7;
        int row = ln & 15;
        int k = ks*32 + (ln >> 4)*8 + j;
        wROP[idx] = f2bf(row_w[l*1024 + k*16 + row]);
    } else if (g < 81920 + O_) {                      // orientations
        int o = g - 81920;
        float vx, vy, vz;
        fib_vec(o, vx, vy, vz);
        orig[o*3+0] = vx; orig[o*3+1] = vy; orig[o*3+2] = vz;
    }
}

// ---------------------------------------------------------------------------
// Fiber-basis precompute: one wave per orientation pair.
// ---------------------------------------------------------------------------
__global__ __launch_bounds__(256) void k_fibpre(
    const float* __restrict__ fw1, const float* __restrict__ fb1,
    const float* __restrict__ fw2, const float* __restrict__ fb2,
    const float* __restrict__ cfw, float* __restrict__ fkg)
{
    __shared__ float sRow[4][64];
    const int wv = threadIdx.x >> 6, lane = threadIdx.x & 63;
    const int pr = blockIdx.x * 4 + wv;
    if (pr >= 100) return;
    const int i = pr / O_, j = pr % O_;
    float ix, iy, iz, jx, jy, jz;
    fib_vec(i, ix, iy, iz);
    fib_vec(j, jx, jy, jz);
    float a = ix*jx + iy*jy + iz*jz;
    float a2 = a*a, a3 = a2*a, a4 = a3*a;
    float v = fb1[lane];
    v = fmaf(a,  fw1[0*64+lane], v);
    v = fmaf(a2, fw1[1*64+lane], v);
    v = fmaf(a3, fw1[2*64+lane], v);
    v = fmaf(a4, fw1[3*64+lane], v);
    sRow[wv][lane] = gelu_f(v);
    float acc = fb2[lane];
    for (int b = 0; b < 64; ++b) acc = fmaf(sRow[wv][b], fw2[b*64+lane], acc);
    sRow[wv][lane] = gelu_f(acc);
    for (int l = 0; l < 2; ++l) {
        float s = 0.0f;
        for (int b = 0; b < 64; ++b) s = fmaf(sRow[wv][b], cfw[l*4096 + b*64 + lane], s);
        fkg[l*6400 + pr*64 + lane] = s;
    }
}

// ---------------------------------------------------------------------------
// Embed: compact hg0[n][c] fp32 (initial h is o-uniform) + bf16 table hbf0.
// ---------------------------------------------------------------------------
__global__ __launch_bounds__(256) void k_embed(
    const float* __restrict__ x, const float* __restrict__ ew,
    float* __restrict__ hg0, unsigned short* __restrict__ hbf0)
{
    int t = blockIdx.x * 256 + threadIdx.x;
    if (t >= N_ * 64) return;
    int n = t >> 6, c = t & 63;
    float v = 0.0f;
#pragma unroll
    for (int k = 0; k < 16; ++k) v = fmaf(x[n*16+k], ew[k*64+c], v);
    hg0[t] = v;
    hbf0[t] = f2bf(v);
}

// ---------------------------------------------------------------------------
__global__ __launch_bounds__(256) void k_hist(const int* __restrict__ ei, int* __restrict__ counts)
{
    int e = blockIdx.x * 256 + threadIdx.x;
    if (e < E_) atomicAdd(&counts[ei[E_ + e]], 1);
}

__global__ __launch_bounds__(1024) void k_scan(
    const int* __restrict__ counts, int* __restrict__ offs, int* __restrict__ cursor)
{
    __shared__ int part[1024];
    int t = threadIdx.x;
    const int CH = 10;
    int base_i = t * CH;
    int s = 0;
#pragma unroll
    for (int i = 0; i < CH; ++i) { int idx = base_i + i; if (idx < N_) s += counts[idx]; }
    part[t] = s;
    __syncthreads();
    for (int off = 1; off < 1024; off <<= 1) {
        int v = (t >= off) ? part[t - off] : 0;
        __syncthreads();
        part[t] += v;
        __syncthreads();
    }
    int run = (t > 0) ? part[t - 1] : 0;
#pragma unroll
    for (int i = 0; i < CH; ++i) {
        int idx = base_i + i;
        if (idx < N_) { offs[idx] = run; cursor[idx] = run; run += counts[idx]; }
    }
    if (t == 1023) offs[N_] = run;
}

__global__ __launch_bounds__(256) void k_scatter(
    const int* __restrict__ ei, const float* __restrict__ pos,
    int* __restrict__ cursor, int* __restrict__ csend, int* __restrict__ crecv,
    float* __restrict__ crel)
{
    int e = blockIdx.x * 256 + threadIdx.x;
    if (e >= E_) return;
    int s = ei[e], r = ei[E_ + e];
    int slot = atomicAdd(&cursor[r], 1);
    csend[slot] = s;
    crecv[slot] = r;
    crel[slot*3+0] = pos[s*3+0] - pos[r*3+0];
    crel[slot*3+1] = pos[s*3+1] - pos[r*3+1];
    crel[slot*3+2] = pos[s*3+2] - pos[r*3+2];
}

// ---------------------------------------------------------------------------
// MFMA stage helpers (single-wave block: rows 0..63 of sData).
// ---------------------------------------------------------------------------
template<int KS>
__device__ __forceinline__ void loadB(
    const unsigned short* sData, int lane, bf16x8 Bf[4][KS])
{
    const int lm = lane & 15, lk = lane >> 4;
#pragma unroll
    for (int nt = 0; nt < 4; ++nt)
#pragma unroll
        for (int ks = 0; ks < KS; ++ks) {
            int r = nt*16 + lm;
            int kb = ks*64 + lk*16;
            Bf[nt][ks] = *(const bf16x8*)((const char*)sData + r*128 + (kb ^ ((r&7)<<4)));
        }
}

template<int KS, bool BIAS, bool GELU>
__device__ __forceinline__ void stageC(
    unsigned short* sData, const bf16x8 Bf[4][KS],
    const unsigned short* __restrict__ Wp, const float* __restrict__ bias, int lane)
{
    const int lm = lane & 15, lk = lane >> 4;
#pragma unroll
    for (int mt = 0; mt < 4; ++mt) {
        bf16x8 Af[KS];
#pragma unroll
        for (int ks = 0; ks < KS; ++ks)
            Af[ks] = *(const bf16x8*)(Wp + ((mt*KS + ks)*64 + lane)*8);
        f32x4 b4 = {0,0,0,0};
        if (BIAS) b4 = *(const f32x4*)(bias + mt*16 + (lk<<2));
#pragma unroll
        for (int nt = 0; nt < 4; ++nt) {
            f32x4 acc = b4;
#pragma unroll
            for (int ks = 0; ks < KS; ++ks) acc = MFMA16(Af[ks], Bf[nt][ks], acc);
            float v0 = acc[0], v1 = acc[1], v2 = acc[2], v3 = acc[3];
            if (GELU) { v0 = gelu_f(v0); v1 = gelu_f(v1); v2 = gelu_f(v2); v3 = gelu_f(v3); }
            bf16x4 pk = pack4(v0, v1, v2, v3);
            int rr = nt*16 + lm;
            int cb = mt*32 + (lk<<3);
            *(bf16x4*)((char*)sData + rr*128 + (cb ^ ((rr&7)<<4))) = pk;
        }
    }
}

// phase 0: per-item monomial features -> sData row tid
__device__ __forceinline__ void phase0(
    unsigned short* sData, int slot, int oo, const float* __restrict__ crel,
    const float* __restrict__ ori, int tid)
{
    float r0 = crel[slot*3+0], r1 = crel[slot*3+1], r2 = crel[slot*3+2];
    float o0 = ori[oo*3+0], o1 = ori[oo*3+1], o2 = ori[oo*3+2];
    float a = r0*o0 + r1*o1 + r2*o2;
    float p0 = fmaf(-a, o0, r0), p1 = fmaf(-a, o1, r1), p2 = fmaf(-a, o2, r2);
    float b = sqrtf(p0*p0 + p1*p1 + p2*p2);
    float a2 = a*a, b2 = b*b, ab = a*b;
    float m[14];
    m[0]=a; m[1]=b; m[2]=a2; m[3]=ab; m[4]=b2;
    m[5]=a2*a; m[6]=a2*b; m[7]=a*b2; m[8]=b2*b;
    m[9]=a2*a2; m[10]=a2*ab; m[11]=a2*b2; m[12]=ab*b2; m[13]=b2*b2;
    unsigned int pk[16];
#pragma unroll
    for (int j = 0; j < 7; ++j) pk[j] = cvtpk(m[2*j], m[2*j+1]);
#pragma unroll
    for (int j = 7; j < 16; ++j) pk[j] = 0;
#pragma unroll
    for (int q = 0; q < 4; ++q) {
        int cb = q*16;
        *(f32x4*)((char*)sData + tid*128 + (cb ^ ((tid&7)<<4))) = ((const f32x4*)pk)[q];
    }
}

// scatter tail: lane=channel.
#define SCATTER_BODY(KC_EXPR)                                                        \
    int prevr = __shfl_up(rcv, 1);                                                   \
    unsigned long long bmask = __ballot(lane > 0 && rcv != prevr);                   \
    float a0=0,a1c=0,a2c=0,a3c=0,a4c=0,a5c=0,a6c=0,a7c=0,a8c=0,a9c=0;                \
    int cur = __builtin_amdgcn_readfirstlane(rcv);                                   \
    int soi = item0 % 10;                                                            \
    _Pragma("unroll")                                                                \
    for (int ch = 0; ch < 4; ++ch) {                                                 \
        unsigned short hvu[16]; float kcv[16];                                       \
        _Pragma("unroll")                                                            \
        for (int j = 0; j < 16; ++j) {                                               \
            const int i = ch*16 + j;                                                 \
            hvu[j] = hb[__builtin_amdgcn_readlane(myaddr, i)];                       \
            kcv[j] = (KC_EXPR);                                                      \
        }                                                                            \
        _Pragma("unroll")                                                            \
        for (int j = 0; j < 16; ++j) {                                               \
            const int i = ch*16 + j;                                                 \
            if (bmask & (1ull << i)) { FLUSH_RUN(cur); cur = __builtin_amdgcn_readlane(rcv, i); } \
            float mv = kcv[j] * bf2f(hvu[j]);                                        \
            if      (soi == 0) a0  += mv;                                            \
            else if (soi == 1) a1c += mv;                                            \
            else if (soi == 2) a2c += mv;                                            \
            else if (soi == 3) a3c += mv;                                            \
            else if (soi == 4) a4c += mv;                                            \
            else if (soi == 5) a5c += mv;                                            \
            else if (soi == 6) a6c += mv;                                            \
            else if (soi == 7) a7c += mv;                                            \
            else if (soi == 8) a8c += mv;                                            \
            else               a9c += mv;                                            \
            soi = (soi == 9) ? 0 : soi + 1;                                          \
        }                                                                            \
    }                                                                                \
    FLUSH_RUN(cur);

#define FLUSH_RUN(R) { float* bp = h1g + (R)*640 + lane; \
    atomicAdd(bp+0,a0); atomicAdd(bp+64,a1c); atomicAdd(bp+128,a2c); atomicAdd(bp+192,a3c); \
    atomicAdd(bp+256,a4c); atomicAdd(bp+320,a5c); atomicAdd(bp+384,a6c); atomicAdd(bp+448,a7c); \
    atomicAdd(bp+512,a8c); atomicAdd(bp+576,a9c); \
    a0=a1c=a2c=a3c=a4c=a5c=a6c=a7c=a8c=a9c=0.0f; }

// ---------------------------------------------------------------------------
// Fallback full k_msg (1 wave/block, 8 KB LDS).  L0: gather hbf0[n][c].
// ---------------------------------------------------------------------------
template<bool L0>
__global__ __launch_bounds__(64) void k_msg(
    const unsigned short* __restrict__ hbf, float* __restrict__ h1g,
    const int* __restrict__ csend, const int* __restrict__ crecv,
    const float* __restrict__ crel, const float* __restrict__ ori,
    const unsigned short* __restrict__ wW1P, const unsigned short* __restrict__ wW2P,
    const unsigned short* __restrict__ wCKP_l,
    const float* __restrict__ bb1, const float* __restrict__ bb2)
{
    __shared__ unsigned short sData[64*64];
    const int lane = threadIdx.x;
    const int item0 = blockIdx.x * 64;
    const int item = item0 + lane;
    const int slot = item / 10;
    const int oo = item - slot * 10;
    const int snd = csend[slot];
    const int rcv = crecv[slot];
    phase0(sData, slot, oo, crel, ori, lane);
    {
        bf16x8 Bf1[4][1]; loadB<1>(sData, lane, Bf1);
        stageC<1, true, true>(sData, Bf1, wW1P, bb1, lane);
    }
    {
        bf16x8 Bf2[4][2]; loadB<2>(sData, lane, Bf2);
        stageC<2, true, true>(sData, Bf2, wW2P, bb2, lane);
    }
    {
        bf16x8 Bf3[4][2]; loadB<2>(sData, lane, Bf3);
        stageC<2, false, false>(sData, Bf3, wCKP_l, (const float*)0, lane);
    }
    const int myaddr = L0 ? (snd * 64) : ((snd * 10 + oo) * 64);
    const unsigned short* hb = hbf + lane;
    const char* vb[8];
#pragma unroll
    for (int k = 0; k < 8; ++k) vb[k] = (const char*)sData + ((lane*2) ^ (k<<4));
    SCATTER_BODY(bf2f(*(const unsigned short*)(vb[j&7] + i*128)))
}

// ---------------------------------------------------------------------------
// Layer-0 dual k_msg: shared stages 1-2, stage3 for BOTH layers; kc1 -> global
// (de-swizzled, coalesced 1KB stores), kc0 -> scatter with hbf0.
// ---------------------------------------------------------------------------
__global__ __launch_bounds__(64) void k_msg0dual(
    const unsigned short* __restrict__ hbf, float* __restrict__ h1g,
    unsigned short* __restrict__ kc1g,
    const int* __restrict__ csend, const int* __restrict__ crecv,
    const float* __restrict__ crel, const float* __restrict__ ori,
    const unsigned short* __restrict__ wW1P, const unsigned short* __restrict__ wW2P,
    const unsigned short* __restrict__ wCK0, const unsigned short* __restrict__ wCK1,
    const float* __restrict__ bb1, const float* __restrict__ bb2)
{
    __shared__ unsigned short sData[64*64];
    const int lane = threadIdx.x;
    const int item0 = blockIdx.x * 64;
    const int item = item0 + lane;
    const int slot = item / 10;
    const int oo = item - slot * 10;
    const int snd = csend[slot];
    const int rcv = crecv[slot];
    phase0(sData, slot, oo, crel, ori, lane);
    {
        bf16x8 Bf1[4][1]; loadB<1>(sData, lane, Bf1);
        stageC<1, true, true>(sData, Bf1, wW1P, bb1, lane);
    }
    {
        bf16x8 Bf2[4][2]; loadB<2>(sData, lane, Bf2);
        stageC<2, true, true>(sData, Bf2, wW2P, bb2, lane);
    }
    bf16x8 Bf3[4][2]; loadB<2>(sData, lane, Bf3);
    // stage3 layer 1 -> kc1g: de-swizzling copy, 1KB contiguous stores.
    stageC<2, false, false>(sData, Bf3, wCK1, (const float*)0, lane);
    {
        char* dst = (char*)kc1g + (size_t)item0 * 128;
#pragma unroll
        for (int q = 0; q < 8; ++q) {
            int g = q*1024 + lane*16;
            int row = g >> 7;
            int off = g & 127;
            f32x4 v = *(const f32x4*)((const char*)sData + row*128 + (off ^ ((row&7)<<4)));
            *(f32x4*)(dst + g) = v;
        }
    }
    // stage3 layer 0 -> scatter
    stageC<2, false, false>(sData, Bf3, wCK0, (const float*)0, lane);
    const int myaddr = snd * 64;
    const unsigned short* hb = hbf + lane;
    const char* vb[8];
#pragma unroll
    for (int k = 0; k < 8; ++k) vb[k] = (const char*)sData + ((lane*2) ^ (k<<4));
    SCATTER_BODY(bf2f(*(const unsigned short*)(vb[j&7] + i*128)))
}

// ---------------------------------------------------------------------------
// Layer-1 lite k_msg: precomputed kc1 (plain row-major) + gather + scatter.
// ---------------------------------------------------------------------------
__global__ __launch_bounds__(64) void k_msg1lite(
    const unsigned short* __restrict__ kc1g, const unsigned short* __restrict__ hbf,
    float* __restrict__ h1g,
    const int* __restrict__ csend, const int* __restrict__ crecv)
{
    const int lane = threadIdx.x;
    const int item0 = blockIdx.x * 64;
    const int item = item0 + lane;
    const int slot = item / 10;
    const int oo = item - slot * 10;
    const int snd = csend[slot];
    const int rcv = crecv[slot];
    const int myaddr = (snd * 10 + oo) * 64;
    const unsigned short* hb = hbf + lane;
    const char* kb = (const char*)kc1g + (size_t)item0 * 128 + lane*2;
    SCATTER_BODY(bf2f(*(const unsigned short*)(kb + (size_t)i*128)))
}
#undef FLUSH_RUN
#undef SCATTER_BODY

// ---------------------------------------------------------------------------
// Fused fiber conv + LayerNorm -> y bf16; optionally zero h1 after read.
// ---------------------------------------------------------------------------
__global__ __launch_bounds__(256) void k_fln(
    float* __restrict__ h1, const float* __restrict__ fkg,
    const float* __restrict__ cb, const float* __restrict__ ns,
    const float* __restrict__ nb, unsigned short* __restrict__ y, int zero_h1)
{
    __shared__ float sFK[6400];
    const int tid = threadIdx.x;
    for (int i = tid; i < 6400; i += 256) sFK[i] = fkg[i];
    __syncthreads();
    const int lane = tid & 63, wv = tid >> 6;
    float cbv = cb[lane], nsv = ns[lane], nbv = nb[lane];
    const int n = blockIdx.x * 4 + wv;
    float hr[10];
#pragma unroll
    for (int o = 0; o < O_; ++o) hr[o] = h1[n*640 + o*64 + lane];
    if (zero_h1) {
#pragma unroll
        for (int o = 0; o < O_; ++o) h1[n*640 + o*64 + lane] = 0.0f;
    }
#pragma unroll
    for (int p = 0; p < O_; ++p) {
        float v = 0.0f;
#pragma unroll
        for (int o = 0; o < O_; ++o) v = fmaf(hr[o], sFK[(p*O_+o)*64 + lane], v);
        v = v * 0.1f + cbv;
        float s = v, q = v*v;
#pragma unroll
        for (int d = 1; d < 64; d <<= 1) { s += __shfl_xor(s, d); q += __shfl_xor(q, d); }
        float mu = s * (1.0f/64.0f);
        float var = q * (1.0f/64.0f) - mu*mu;
        float rs = rsqrtf(var + 1e-6f);
        float yv = (v - mu) * rs * nsv + nbv;
        y[(n*O_ + p)*64 + lane] = f2bf(yv);
    }
}

// ---------------------------------------------------------------------------
// MLP: 128 rows/block (nt=2), frag-packed weights, readout stored.
// LAST=0: residual from compact hg0[n] (o-uniform initial h), write hn to hg
// (fp32) and ybuf (bf16, next layer's gather).  LAST=1: residual from hg,
// no write-back.
// ---------------------------------------------------------------------------
template<int LAST>
__global__ __launch_bounds__(256, 4) void k_mlp(
    unsigned short* ybuf, const float* __restrict__ hread, float* __restrict__ hg,
    float* __restrict__ rout,
    const unsigned short* __restrict__ wL1P_l, const float* __restrict__ l1b_l,
    const unsigned short* __restrict__ wL2P_l, const float* __restrict__ l2b_l,
    const unsigned short* __restrict__ wROP_l, const float* __restrict__ rob_l)
{
    __shared__ unsigned short sA[128*64];
    const int tid = threadIdx.x;
    const int lane = tid & 63, wv = tid >> 6;
    const int rb = blockIdx.x * 128;
#pragma unroll
    for (int i = tid*16; i < 128*128; i += 256*16) {
        int r = i >> 7, off = i & 127;
        int grow = rb + r; if (grow >= NROW_) grow = NROW_ - 1;
        *(f32x4*)((char*)sA + r*128 + (off ^ ((r&7)<<4))) =
            *(const f32x4*)((const char*)ybuf + (size_t)grow*128 + off);
    }
    __syncthreads();
    const int lm = lane & 15, lk = lane >> 4;
    bf16x8 Yf[2][2];
#pragma unroll
    for (int nt = 0; nt < 2; ++nt)
#pragma unroll
        for (int ks = 0; ks < 2; ++ks) {
            int r = wv*32 + nt*16 + lm;
            int kb = ks*64 + lk*16;
            Yf[nt][ks] = *(const bf16x8*)((const char*)sA + r*128 + (kb ^ ((r&7)<<4)));
        }
    f32x4 acc2[4][2];
#pragma unroll
    for (int m = 0; m < 4; ++m) {
        f32x4 b2 = *(const f32x4*)(l2b_l + m*16 + (lk<<2));
#pragma unroll
        for (int nt = 0; nt < 2; ++nt) acc2[m][nt] = b2;
    }
#pragma unroll
    for (int jb = 0; jb < 4; ++jb) {
#pragma unroll
        for (int mt = 0; mt < 4; ++mt) {
            bf16x8 A1[2];
#pragma unroll
            for (int ks = 0; ks < 2; ++ks)
                A1[ks] = *(const bf16x8*)(wL1P_l + (((jb*4 + mt)*2 + ks)*64 + lane)*8);
            f32x4 b4 = *(const f32x4*)(l1b_l + jb*64 + mt*16 + (lk<<2));
#pragma unroll
            for (int nt = 0; nt < 2; ++nt) {
                f32x4 acc = b4;
                acc = MFMA16(A1[0], Yf[nt][0], acc);
                acc = MFMA16(A1[1], Yf[nt][1], acc);
                bf16x4 pk = pack4(gelu_f(acc[0]), gelu_f(acc[1]), gelu_f(acc[2]), gelu_f(acc[3]));
                int rr = wv*32 + nt*16 + lm;
                int cb = mt*32 + (lk<<3);
                *(bf16x4*)((char*)sA + rr*128 + (cb ^ ((rr&7)<<4))) = pk;
            }
        }
        bf16x8 Mf[2][2];
#pragma unroll
        for (int nt = 0; nt < 2; ++nt)
#pragma unroll
            for (int ks = 0; ks < 2; ++ks) {
                int r = wv*32 + nt*16 + lm;
                int kb = ks*64 + lk*16;
                Mf[nt][ks] = *(const bf16x8*)((const char*)sA + r*128 + (kb ^ ((r&7)<<4)));
            }
#pragma unroll
        for (int mt2 = 0; mt2 < 4; ++mt2) {
            bf16x8 A2[2];
#pragma unroll
            for (int ks = 0; ks < 2; ++ks)
                A2[ks] = *(const bf16x8*)(wL2P_l + ((mt2*8 + jb*2 + ks)*64 + lane)*8);
#pragma unroll
            for (int nt = 0; nt < 2; ++nt) {
                acc2[mt2][nt] = MFMA16(A2[0], Mf[nt][0], acc2[mt2][nt]);
                acc2[mt2][nt] = MFMA16(A2[1], Mf[nt][1], acc2[mt2][nt]);
            }
        }
    }
    // epilogue: residual + hn stash
#pragma unroll
    for (int nt = 0; nt < 2; ++nt) {
        const int rloc = wv*32 + nt*16 + lm;
        const int grow = rb + rloc;
        const bool valid = grow < NROW_;
        const int growc = valid ? grow : (NROW_ - 1);
        const size_t hoff = LAST ? ((size_t)growc*64) : ((size_t)(growc/10)*64);
#pragma unroll
        for (int mt2 = 0; mt2 < 4; ++mt2) {
            f32x4 hv = *(const f32x4*)(hread + hoff + mt2*16 + (lk<<2));
            f32x4 hn;
#pragma unroll
            for (int r = 0; r < 4; ++r) hn[r] = hv[r] + acc2[mt2][nt][r];
            bf16x4 pk = pack4(hn[0], hn[1], hn[2], hn[3]);
            if (!LAST && valid) {
                *(f32x4*)(hg + (size_t)grow*64 + mt2*16 + (lk<<2)) = hn;
                *(bf16x4*)((char*)ybuf + (size_t)grow*128 + (mt2*16 + (lk<<2))*2) = pk;
            }
            int cb = mt2*32 + (lk<<3);
            *(bf16x4*)((char*)sA + rloc*128 + (cb ^ ((rloc&7)<<4))) = pk;
        }
    }
    // readout: ro^T hn -> store
    bf16x8 Ro[2];
#pragma unroll
    for (int ks = 0; ks < 2; ++ks)
        Ro[ks] = *(const bf16x8*)(wROP_l + (ks*64 + lane)*8);
    f32x4 rb4 = *(const f32x4*)(rob_l + (lk<<2));
#pragma unroll
    for (int nt = 0; nt < 2; ++nt) {
        const int rloc = wv*32 + nt*16 + lm;
        const int grow = rb + rloc;
        bf16x8 Hf[2];
#pragma unroll
        for (int ks = 0; ks < 2; ++ks) {
            int kb = ks*64 + lk*16;
            Hf[ks] = *(const bf16x8*)((const char*)sA + rloc*128 + (kb ^ ((rloc&7)<<4)));
        }
        f32x4 r4 = rb4;
        r4 = MFMA16(Ro[0], Hf[0], r4);
        r4 = MFMA16(Ro[1], Hf[1], r4);
        if (grow < NROW_) *(f32x4*)(rout + (size_t)grow*16 + (lk<<2)) = r4;
    }
}

// ---------------------------------------------------------------------------
__global__ __launch_bounds__(256) void k_pool(
    const float* __restrict__ r0, const float* __restrict__ r1,
    const int* __restrict__ batch, float* __restrict__ out)
{
    int t = blockIdx.x * 256 + threadIdx.x;
    if (t >= N_ * 16) return;
    int n = t >> 4, j = t & 15;
    float s = 0.0f;
#pragma unroll
    for (int p = 0; p < O_; ++p)
        s += r0[(n*O_ + p)*16 + j] + r1[(n*O_ + p)*16 + j];
    atomicAdd(&out[batch[n]*16 + j], s * (1.0f/20.0f));
}

// ---------------------------------------------------------------------------
extern "C" void kernel_launch(void* const* d_in, const int* in_sizes, int n_in,
                              void* d_out, int out_size, void* d_ws, size_t ws_size,
                              hipStream_t stream)
{
    const float* x    = (const float*)d_in[0];
    const float* pos  = (const float*)d_in[1];
    const float* bw1  = (const float*)d_in[2];
    const float* bb1  = (const float*)d_in[3];
    const float* bw2  = (const float*)d_in[4];
    const float* bb2  = (const float*)d_in[5];
    const float* fw1  = (const float*)d_in[6];
    const float* fb1  = (const float*)d_in[7];
    const float* fw2  = (const float*)d_in[8];
    const float* fb2  = (const float*)d_in[9];
    const float* embw = (const float*)d_in[10];
    const float* ckw  = (const float*)d_in[11];
    const float* cfw  = (const float*)d_in[12];
    const float* cb   = (const float*)d_in[13];
    const float* ns   = (const float*)d_in[14];
    const float* nbp  = (const float*)d_in[15];
    const float* l1w  = (const float*)d_in[16];
    const float* l1b  = (const float*)d_in[17];
    const float* l2w  = (const float*)d_in[18];
    const float* l2b  = (const float*)d_in[19];
    const float* row  = (const float*)d_in[20];
    const float* rob  = (const float*)d_in[21];
    const int*   ei   = (const int*)d_in[22];
    const int*   batch= (const int*)d_in[23];
    float* out = (float*)d_out;

    char* w = (char*)d_ws;
    size_t off = 0;
    auto alloc = [&](size_t bytes) -> char* {
        char* p = w + off; off += (bytes + 255) / 256 * 256; return p;
    };
    float* ori    = (float*)alloc(32 * 4);
    float* fkg    = (float*)alloc(2 * 6400 * 4);
    unsigned short* wW1P = (unsigned short*)alloc(4*512*2);
    unsigned short* wW2P = (unsigned short*)alloc(8*512*2);
    unsigned short* wCKP = (unsigned short*)alloc(2*8*512*2);
    unsigned short* wL1P = (unsigned short*)alloc(2*32*512*2);
    unsigned short* wL2P = (unsigned short*)alloc(2*32*512*2);
    unsigned short* wROP = (unsigned short*)alloc(2*2*512*2);
    float* hg0    = (float*)alloc((size_t)N_ * 64 * 4);
    float* h      = (float*)alloc((size_t)NROW_ * 64 * 4);
    float* h1     = (float*)alloc((size_t)N_ * 640 * 4);
    unsigned short* y = (unsigned short*)alloc((size_t)NROW_ * 64 * 2);
    unsigned short* hbf0 = (unsigned short*)alloc((size_t)N_ * 64 * 2);
    float* rout0  = (float*)alloc((size_t)NROW_ * 16 * 4);
    float* rout1  = (float*)alloc((size_t)NROW_ * 16 * 4);
    float* crel   = (float*)alloc((size_t)E_ * 3 * 4);
    int*   counts = (int*)alloc((N_ + 1) * 4);
    int*   offs   = (int*)alloc((N_ + 1) * 4);
    int*   cursor = (int*)alloc((N_ + 1) * 4);
    int*   csend  = (int*)alloc((size_t)E_ * 4);
    int*   crecv  = (int*)alloc((size_t)E_ * 4);
    // optional kc1 buffer (102.4 MB) -- split path only if workspace allows
    unsigned short* kc1g = nullptr;
    if (ws_size >= off + (size_t)NITEM_ * 64 * 2 + 256)
        kc1g = (unsigned short*)alloc((size_t)NITEM_ * 64 * 2);

    hipMemsetAsync(h1, 0, (size_t)N_ * 640 * 4, stream);
    hipMemsetAsync(out, 0, (size_t)out_size * 4, stream);
    hipMemsetAsync(counts, 0, (N_ + 1) * 4, stream);

    k_pack<<<321, 256, 0, stream>>>(bw1, bw2, ckw, l1w, l2w, row, ori,
                                    wW1P, wW2P, wCKP, wL1P, wL2P, wROP);
    k_fibpre<<<25, 256, 0, stream>>>(fw1, fb1, fw2, fb2, cfw, fkg);
    k_embed<<<(N_ * 64 + 255) / 256, 256, 0, stream>>>(x, embw, hg0, hbf0);
    k_hist<<<(E_ + 255) / 256, 256, 0, stream>>>(ei, counts);
    k_scan<<<1, 1024, 0, stream>>>(counts, offs, cursor);
    k_scatter<<<(E_ + 255) / 256, 256, 0, stream>>>(ei, pos, cursor, csend, crecv, crel);

    for (int l = 0; l < 2; ++l) {
        if (l == 0) {
            if (kc1g)
                k_msg0dual<<<NITEM_ / 64, 64, 0, stream>>>(hbf0, h1, kc1g, csend, crecv,
                                                           crel, ori, wW1P, wW2P,
                                                           wCKP, wCKP + 4096, bb1, bb2);
            else
                k_msg<true><<<NITEM_ / 64, 64, 0, stream>>>(hbf0, h1, csend, crecv, crel, ori,
                                                            wW1P, wW2P, wCKP, bb1, bb2);
        } else {
            if (kc1g)
                k_msg1lite<<<NITEM_ / 64, 64, 0, stream>>>(kc1g, y, h1, csend, crecv);
            else
                k_msg<false><<<NITEM_ / 64, 64, 0, stream>>>(y, h1, csend, crecv, crel, ori,
                                                             wW1P, wW2P, wCKP + 4096, bb1, bb2);
        }
        k_fln<<<N_ / 4, 256, 0, stream>>>(h1, fkg + l*6400, cb + l*64, ns + l*64, nbp + l*64, y,
                                          (l == 0) ? 1 : 0);
        if (l == 0)
            k_mlp<0><<<(NROW_ + 127) / 128, 256, 0, stream>>>(y, hg0, h, rout0,
                                                              wL1P, l1b, wL2P, l2b,
                                                              wROP, rob);
        else
            k_mlp<1><<<(NROW_ + 127) / 128, 256, 0, stream>>>(y, h, h, rout1,
                                                              wL1P + 16384, l1b + 256,
                                                              wL2P + 16384, l2b + 64,
                                                              wROP + 1024, rob + 16);
    }
    k_pool<<<(N_ * 16 + 255) / 256, 256, 0, stream>>>(rout0, rout1, batch, out);
}